// Round 1
// baseline (257.585 us; speedup 1.0000x reference)
//
#include <hip/hip_runtime.h>

// Problem constants
#define BATCH   8
#define NNODES  16384
#define KNBR    16
#define LATENT  128
#define DOUT    32
#define NROWS   (BATCH * NNODES)          // 131072 rows total
#define WPAD    132                        // 128 + 4 pad: stride*4B = 528B, 16B aligned, breaks bank conflicts

// ---------------------------------------------------------------------------
// Kernel 1: fused ks/qs projection.  out[row][d] = dot(features[row], w[d]) + b[d]
// Tile: 256 threads/block, each thread computes 8 rows x (4 ks-d + 4 qs-d).
// 256 rows per block -> grid = 512 blocks.
// ---------------------------------------------------------------------------
__global__ __launch_bounds__(256) void proj_kernel(
    const float* __restrict__ feats,
    const float* __restrict__ kw, const float* __restrict__ kb,
    const float* __restrict__ qw, const float* __restrict__ qb,
    float* __restrict__ out_k, float* __restrict__ out_q)
{
    __shared__ float wk[DOUT * WPAD];
    __shared__ float wq[DOUT * WPAD];
    const int tid = threadIdx.x;

    // Stage weights into LDS (coalesced read, conflict-free write: consecutive l)
    for (int i = tid; i < DOUT * LATENT; i += 256) {
        int d = i >> 7;          // /128
        int l = i & 127;
        wk[d * WPAD + l] = kw[i];
        wq[d * WPAD + l] = qw[i];
    }
    __syncthreads();

    const int d0 = tid & 7;      // output-quad group: d = 4*d0 + j
    const int ro = tid >> 3;     // row group: 8 rows
    const long long rbase = (long long)blockIdx.x * 256 + (long long)ro * 8;

    float acc_k[8][4];
    float acc_q[8][4];
#pragma unroll
    for (int i = 0; i < 8; ++i)
#pragma unroll
        for (int j = 0; j < 4; ++j) { acc_k[i][j] = 0.f; acc_q[i][j] = 0.f; }

    const float4* f4 = (const float4*)feats;

    for (int lc = 0; lc < LATENT / 4; ++lc) {
        const int l = lc * 4;
        float4 w_k[4], w_q[4];
#pragma unroll
        for (int j = 0; j < 4; ++j) {
            w_k[j] = *(const float4*)&wk[(4 * d0 + j) * WPAD + l];
            w_q[j] = *(const float4*)&wq[(4 * d0 + j) * WPAD + l];
        }
#pragma unroll
        for (int i = 0; i < 8; ++i) {
            const float4 f = f4[(rbase + i) * (LATENT / 4) + lc];
#pragma unroll
            for (int j = 0; j < 4; ++j) {
                acc_k[i][j] += f.x * w_k[j].x + f.y * w_k[j].y + f.z * w_k[j].z + f.w * w_k[j].w;
                acc_q[i][j] += f.x * w_q[j].x + f.y * w_q[j].y + f.z * w_q[j].z + f.w * w_q[j].w;
            }
        }
    }

    // Epilogue: add bias, store float4 per row (row stride = 32 floats = 8 float4)
    const float4 bk = *(const float4*)&kb[4 * d0];
    const float4 bq = *(const float4*)&qb[4 * d0];
#pragma unroll
    for (int i = 0; i < 8; ++i) {
        float4 vk, vq;
        vk.x = acc_k[i][0] + bk.x; vk.y = acc_k[i][1] + bk.y;
        vk.z = acc_k[i][2] + bk.z; vk.w = acc_k[i][3] + bk.w;
        vq.x = acc_q[i][0] + bq.x; vq.y = acc_q[i][1] + bq.y;
        vq.z = acc_q[i][2] + bq.z; vq.w = acc_q[i][3] + bq.w;
        ((float4*)out_k)[(rbase + i) * (DOUT / 4) + d0] = vk;
        ((float4*)out_q)[(rbase + i) * (DOUT / 4) + d0] = vq;
    }
}

// ---------------------------------------------------------------------------
// Kernel 2: gather + scaled dot product.
// out[b,n,k] = sum_d tk[b, idx1[b,n,k], d] * tq[b, idx2[b,n,k], d] * 32^-0.5
// XCD swizzle: blockIdx % 8 == batch so each XCD's L2 holds one batch's 4MB tables.
// ---------------------------------------------------------------------------
__global__ __launch_bounds__(256) void gather_dot_kernel(
    const float* __restrict__ tk, const float* __restrict__ tq,
    const int* __restrict__ idx, float* __restrict__ out)
{
    const long long NK  = (long long)NNODES * KNBR;     // 262144
    const long long BNK = NK * BATCH;                   // 2097152

    const int b     = blockIdx.x & 7;
    const int chunk = blockIdx.x >> 3;
    const long long local = (long long)chunk * 256 + threadIdx.x;  // < NK
    const long long o     = (long long)b * NK + local;

    const int xi = idx[BNK + o];       // channel 1
    const int yi = idx[2 * BNK + o];   // channel 2

    const float4* xr = (const float4*)(tk + ((long long)b * NNODES + xi) * DOUT);
    const float4* yr = (const float4*)(tq + ((long long)b * NNODES + yi) * DOUT);

    float s = 0.f;
#pragma unroll
    for (int j = 0; j < DOUT / 4; ++j) {
        const float4 x = xr[j];
        const float4 y = yr[j];
        s += x.x * y.x + x.y * y.y + x.z * y.z + x.w * y.w;
    }
    out[o] = s * 0.17677669529663687f;   // 32^-0.5
}

// ---------------------------------------------------------------------------
extern "C" void kernel_launch(void* const* d_in, const int* in_sizes, int n_in,
                              void* d_out, int out_size, void* d_ws, size_t ws_size,
                              hipStream_t stream)
{
    const float* feats = (const float*)d_in[0];
    const float* kw    = (const float*)d_in[1];
    const float* kb    = (const float*)d_in[2];
    const float* qw    = (const float*)d_in[3];
    const float* qb    = (const float*)d_in[4];
    const int*   idx   = (const int*)d_in[5];
    float*       out   = (float*)d_out;

    // Workspace: two fp32 tables [B*N, 32] = 16 MB each
    float* tk = (float*)d_ws;
    float* tq = tk + (long long)NROWS * DOUT;

    // Kernel 1: 512 blocks x 256 threads, 256 rows/block
    proj_kernel<<<NROWS / 256, 256, 0, stream>>>(feats, kw, kb, qw, qb, tk, tq);

    // Kernel 2: one thread per output element, batch-major swizzle for XCD L2 locality
    gather_dot_kernel<<<(BATCH * NNODES * KNBR) / 256, 256, 0, stream>>>(tk, tq, idx, out);
}